// Round 6
// baseline (151.192 us; speedup 1.0000x reference)
//
#include <hip/hip_runtime.h>

#pragma clang fp contract(off)

#define IMG_H 512
#define IMG_W 512
#define TW 32                    // per-wave tile width
#define TH 32                    // per-wave tile height
#define WROWS 36                 // TH + 2*2 window rows
#define WCOLS 40                 // 4 + 32 + 4 cols (quad-aligned halo)
#define NTHREADS 256
#define WAVES 4

__device__ __forceinline__ int reflect_idx(int i) {
    // jnp.pad 'reflect': -1 -> 1, 512 -> 510
    i = (i < 0) ? -i : i;
    i = (i >= IMG_H) ? (2 * IMG_H - 2 - i) : i;
    return i;
}

__device__ __forceinline__ float2 gray2(float a0, float a1, float a2,
                                        float b0, float b1, float b2) {
    // bit-identical T_a gray conversion (verified absmax=0.0)
    float2 g;
    g.x = (0.144f * a0 + 0.587f * a1) + 0.299f * a2;
    g.y = (0.144f * b0 + 0.587f * b1) + 0.299f * b2;
    return g;
}

// Per-WAVE independent tiles, NO __syncthreads. Each wave stages its own
// 36x40 window (private LDS region) and computes its own 32x32 outputs.
// Wave-internal ds_write -> ds_read ordering via s_waitcnt lgkmcnt(0)
// (wave lockstep + own-counter completion). Waves free-run and drift out
// of phase -> staging of some waves overlaps fold-chains of others (TLP),
// instead of the whole grid convoying through stage/barrier/compute.
// T_a chains (verified absmax=0.0): rows ascend, dx ascends within row,
// acc starts 0.0f, mean via s*0.04f recip-mul — fold code unchanged.
__global__ __launch_bounds__(NTHREADS) void texdiff_kernel(
        const float* __restrict__ img1,
        const float* __restrict__ img2,
        float* __restrict__ out) {
    __shared__ float2 lds[WAVES][WROWS][WCOLS];   // 4 x 11,520 B = 46,080 B

    const int tid  = threadIdx.x;
    const int w    = tid >> 6;
    const int lane = tid & 63;

    const int b  = blockIdx.z;
    const int x0 = blockIdx.x * (WAVES * TW) + w * TW;   // 0..480, step 32
    const int y0 = blockIdx.y * TH;

    const size_t plane = (size_t)IMG_H * IMG_W;
    const float* i1 = img1 + (size_t)b * 3 * plane;
    const float* i2 = img2 + (size_t)b * 3 * plane;

    float2 (*buf)[WCOLS] = lds[w];

    // ---- stage: 36 rows x 10 quads = 360 items; LDS col i <-> gx = x0-4+i ----
    #pragma unroll
    for (int p = 0; p < 6; ++p) {
        int item = lane + p * 64;
        if (p < 5 || item < 360) {
            int r = item / 10;            // const-div -> magic mul
            int q = item - r * 10;
            int gy  = reflect_idx(y0 - 2 + r);
            int gx0 = x0 - 4 + 4 * q;
            float2 g0, g1, g2, g3;
            if (gx0 >= 0 && gx0 <= IMG_W - 4) {
                const float* pa = i1 + (size_t)gy * IMG_W + gx0;
                const float* pb = i2 + (size_t)gy * IMG_W + gx0;
                float4 A0 = *(const float4*)(pa);
                float4 A1 = *(const float4*)(pa + plane);
                float4 A2 = *(const float4*)(pa + 2 * plane);
                float4 B0 = *(const float4*)(pb);
                float4 B1 = *(const float4*)(pb + plane);
                float4 B2 = *(const float4*)(pb + 2 * plane);
                g0 = gray2(A0.x, A1.x, A2.x, B0.x, B1.x, B2.x);
                g1 = gray2(A0.y, A1.y, A2.y, B0.y, B1.y, B2.y);
                g2 = gray2(A0.z, A1.z, A2.z, B0.z, B1.z, B2.z);
                g3 = gray2(A0.w, A1.w, A2.w, B0.w, B1.w, B2.w);
            } else {
                // reflected edge columns (only x0==0 q==0 or x0==480 q==9)
                float2 gt[4];
                #pragma unroll
                for (int t = 0; t < 4; ++t) {
                    int gx = reflect_idx(gx0 + t);
                    size_t off = (size_t)gy * IMG_W + gx;
                    gt[t] = gray2(i1[off], i1[off + plane], i1[off + 2 * plane],
                                  i2[off], i2[off + plane], i2[off + 2 * plane]);
                }
                g0 = gt[0]; g1 = gt[1]; g2 = gt[2]; g3 = gt[3];
            }
            float4* dst = (float4*)&buf[r][4 * q];   // 32B, 16B-aligned
            dst[0] = make_float4(g0.x, g0.y, g1.x, g1.y);
            dst[1] = make_float4(g2.x, g2.y, g3.x, g3.y);
        }
    }

    // wave-local ordering: all this wave's LDS writes complete before reads.
    asm volatile("s_waitcnt lgkmcnt(0)" ::: "memory");
    __builtin_amdgcn_sched_barrier(0);

    // ---- compute: 2 halves of 32x16; lane = (cx 0..15, ry 0..3) ----
    const int cx = lane & 15;        // col pair: tile cols 2cx, 2cx+1
    const int ry = lane >> 4;

    #pragma unroll
    for (int h = 0; h < 2; ++h) {
        const int r0 = h * 16 + ry * 4;   // output rows r0..r0+3 (local)

        float s1[4][2], q1[4][2], s2[4][2], q2[4][2];
        #pragma unroll
        for (int k = 0; k < 4; ++k) {
            #pragma unroll
            for (int j = 0; j < 2; ++j) {
                s1[k][j] = 0.0f; q1[k][j] = 0.0f;
                s2[k][j] = 0.0f; q2[k][j] = 0.0f;
            }
        }

        // 8 LDS rows serve 4 overlapping windows; row read once (3x b128).
        // LDS float2 idx 2cx+2 .. 2cx+7  <->  gx = x0+2cx-2 .. x0+2cx+3.
        #pragma unroll
        for (int rr = 0; rr < 8; ++rr) {
            const float4* vp = (const float4*)&buf[r0 + rr][2 * cx + 2];
            float4 w0 = vp[0], w1 = vp[1], w2 = vp[2];
            float vx[6], vy[6];
            vx[0] = w0.x; vy[0] = w0.y; vx[1] = w0.z; vy[1] = w0.w;
            vx[2] = w1.x; vy[2] = w1.y; vx[3] = w1.z; vy[3] = w1.w;
            vx[4] = w2.x; vy[4] = w2.y; vx[5] = w2.z; vy[5] = w2.w;

            #pragma unroll
            for (int k = 0; k < 4; ++k) {
                if (rr >= k && rr <= k + 4) {   // compile-time predicate
                    #pragma unroll
                    for (int j = 0; j < 2; ++j) {
                        #pragma unroll
                        for (int dx = 0; dx < 5; ++dx) {
                            float a = vx[dx + j];
                            float c = vy[dx + j];
                            s1[k][j] = s1[k][j] + a;  q1[k][j] = q1[k][j] + a * a;
                            s2[k][j] = s2[k][j] + c;  q2[k][j] = q2[k][j] + c * c;
                        }
                    }
                }
            }
        }

        #pragma unroll
        for (int k = 0; k < 4; ++k) {
            float2 o;
            #pragma unroll
            for (int j = 0; j < 2; ++j) {
                float m1 = s1[k][j] * 0.04f;
                float e1 = q1[k][j] * 0.04f;
                float m2 = s2[k][j] * 0.04f;
                float e2 = q2[k][j] * 0.04f;
                float var1 = fmaxf(e1 - m1 * m1, 0.0f);
                float sd1 = sqrtf(var1 + 1e-9f);
                float var2 = fmaxf(e2 - m2 * m2, 0.0f);
                float sd2 = sqrtf(var2 + 1e-9f);
                float num = (2.0f * sd1) * sd2;
                float den = ((sd1 * sd1 + sd2 * sd2) + 1e-5f) + 1e-8f;
                float val = (num / den > 0.975f) ? 1.0f : 0.0f;
                (j == 0 ? o.x : o.y) = val;
            }
            size_t oidx = ((size_t)b * IMG_H + (y0 + r0 + k)) * IMG_W
                          + (x0 + 2 * cx);
            *reinterpret_cast<float2*>(&out[oidx]) = o;
        }
    }
}

extern "C" void kernel_launch(void* const* d_in, const int* in_sizes, int n_in,
                              void* d_out, int out_size, void* d_ws, size_t ws_size,
                              hipStream_t stream) {
    const float* img1 = (const float*)d_in[0];
    const float* img2 = (const float*)d_in[1];
    float* out = (float*)d_out;
    dim3 grid(IMG_W / (WAVES * TW), IMG_H / TH, 16);   // 4 x 16 x 16 = 1024
    texdiff_kernel<<<grid, dim3(NTHREADS), 0, stream>>>(img1, img2, out);
}